// Round 4
// baseline (135.086 us; speedup 1.0000x reference)
//
#include <hip/hip_runtime.h>
#include <math.h>

namespace {
constexpr int kN = 22;
constexpr int kF = 448;
constexpr int kNP = kN * kN;          // 484
// kernel1 shared pool (floats): corr role needs 22*452 + 44 = 9988 (39.95 KB)
constexpr int kXStr = 452;            // 452%4==0 (16B rows), 452%32==4 (bank spread)
constexpr int kSm1 = kN * kXStr + 2 * kN;   // 9988
// GEMM overlays: As [64][68] transposed + Bs [64][68] = 8704 floats (34.8 KB)
constexpr int kAStr = 68;
constexpr int kBStr = 68;
// kernel2
constexpr int kPStr = 68;
constexpr int kVStr = 68;
}

// =================== kernel 1: projections GEMM + corr ======================
// blocks [0, nGemm): 64x64 SGEMM tiles, 4x4 microtile, reg-prefetched K-chunks
//   C = A(M,448) @ W(448,256); col tiles: 0:a1(+cb1) 1:a2 2:u1(+emb@sw1[0:64],+sb1)
//   3:u2(+emb@sw1[64:128])
// blocks [nGemm, nGemm+B): per-b corr stats + 253 unique |corr| dots -> g (both tris)
__global__ __launch_bounds__(256) void hgc_k1(
    const float* __restrict__ x,
    const float* __restrict__ cw1, const float* __restrict__ cb1,
    const float* __restrict__ emb,
    const float* __restrict__ sw1, const float* __restrict__ sb1,
    float* __restrict__ C, float* __restrict__ g,
    int M, int Mtiles, int nGemm)
{
    __shared__ __align__(16) float sm[kSm1];
    const int tid = threadIdx.x;

    if ((int)blockIdx.x < nGemm) {
        // ---------------- GEMM role ----------------
        float* As = sm;                 // As[k][m], [64][kAStr]
        float* Bs = sm + 64 * kAStr;    // Bs[k][n], [64][kBStr]
        const int bm = blockIdx.x % Mtiles;
        const int bn = blockIdx.x / Mtiles;        // 0..3
        const int m0 = bm * 64;

        const float* Wsrc =
            (bn == 0) ? cw1 :
            (bn == 1) ? cw1 + 448 * 64 :
            (bn == 2) ? sw1 + 128 * 64 :
                        sw1 + 576 * 64;

        const int tm = tid & 15;        // rows tm*4 .. +3
        const int tn = tid >> 4;        // cols tn*4 .. +3
        const int ld_row = tid >> 4;    // staging: row/k index 0..63 (with pass*16)
        const int ld_kq  = tid & 15;    // staging: float4 index within 64

        float acc[4][4];
        #pragma unroll
        for (int i = 0; i < 4; ++i)
            #pragma unroll
            for (int j = 0; j < 4; ++j) acc[i][j] = 0.f;

        float4 rA[4], rB[4];
        // prefetch chunk 0
        #pragma unroll
        for (int p = 0; p < 4; ++p) {
            const int row = ld_row + p * 16;
            int m = m0 + row; if (m >= M) m = M - 1;
            rA[p] = *(const float4*)&x[(size_t)m * kF + ld_kq * 4];
            rB[p] = *(const float4*)&Wsrc[(size_t)row * 64 + ld_kq * 4];
        }

        for (int k0 = 0; k0 < kF; k0 += 64) {
            // commit staged regs to LDS (A transposed)
            #pragma unroll
            for (int p = 0; p < 4; ++p) {
                const int row = ld_row + p * 16;
                As[(ld_kq * 4 + 0) * kAStr + row] = rA[p].x;
                As[(ld_kq * 4 + 1) * kAStr + row] = rA[p].y;
                As[(ld_kq * 4 + 2) * kAStr + row] = rA[p].z;
                As[(ld_kq * 4 + 3) * kAStr + row] = rA[p].w;
                *(float4*)&Bs[row * kBStr + ld_kq * 4] = rB[p];
            }
            __syncthreads();
            // prefetch next chunk (or emb epilogue chunk) while computing
            const int kn = k0 + 64;
            if (kn < kF) {
                #pragma unroll
                for (int p = 0; p < 4; ++p) {
                    const int row = ld_row + p * 16;
                    int m = m0 + row; if (m >= M) m = M - 1;
                    rA[p] = *(const float4*)&x[(size_t)m * kF + kn + ld_kq * 4];
                    rB[p] = *(const float4*)&Wsrc[(size_t)(kn + row) * 64 + ld_kq * 4];
                }
            } else if (bn >= 2) {
                const float* W2 = sw1 + (bn == 2 ? 0 : 64) * 64;
                #pragma unroll
                for (int p = 0; p < 4; ++p) {
                    const int row = ld_row + p * 16;
                    const int r = (m0 + row) % kN;
                    rA[p] = *(const float4*)&emb[(size_t)r * 64 + ld_kq * 4];
                    rB[p] = *(const float4*)&W2[(size_t)row * 64 + ld_kq * 4];
                }
            }
            #pragma unroll 8
            for (int k = 0; k < 64; ++k) {
                const float4 a4 = *(const float4*)&As[k * kAStr + tm * 4];
                const float4 b4 = *(const float4*)&Bs[k * kBStr + tn * 4];
                acc[0][0] = fmaf(a4.x, b4.x, acc[0][0]); acc[0][1] = fmaf(a4.x, b4.y, acc[0][1]);
                acc[0][2] = fmaf(a4.x, b4.z, acc[0][2]); acc[0][3] = fmaf(a4.x, b4.w, acc[0][3]);
                acc[1][0] = fmaf(a4.y, b4.x, acc[1][0]); acc[1][1] = fmaf(a4.y, b4.y, acc[1][1]);
                acc[1][2] = fmaf(a4.y, b4.z, acc[1][2]); acc[1][3] = fmaf(a4.y, b4.w, acc[1][3]);
                acc[2][0] = fmaf(a4.z, b4.x, acc[2][0]); acc[2][1] = fmaf(a4.z, b4.y, acc[2][1]);
                acc[2][2] = fmaf(a4.z, b4.z, acc[2][2]); acc[2][3] = fmaf(a4.z, b4.w, acc[2][3]);
                acc[3][0] = fmaf(a4.w, b4.x, acc[3][0]); acc[3][1] = fmaf(a4.w, b4.y, acc[3][1]);
                acc[3][2] = fmaf(a4.w, b4.z, acc[3][2]); acc[3][3] = fmaf(a4.w, b4.w, acc[3][3]);
            }
            __syncthreads();
        }

        // emb epilogue for u1/u2 tiles: extra K=64 (regs already prefetched)
        if (bn >= 2) {
            #pragma unroll
            for (int p = 0; p < 4; ++p) {
                const int row = ld_row + p * 16;
                As[(ld_kq * 4 + 0) * kAStr + row] = rA[p].x;
                As[(ld_kq * 4 + 1) * kAStr + row] = rA[p].y;
                As[(ld_kq * 4 + 2) * kAStr + row] = rA[p].z;
                As[(ld_kq * 4 + 3) * kAStr + row] = rA[p].w;
                *(float4*)&Bs[row * kBStr + ld_kq * 4] = rB[p];
            }
            __syncthreads();
            #pragma unroll 8
            for (int k = 0; k < 64; ++k) {
                const float4 a4 = *(const float4*)&As[k * kAStr + tm * 4];
                const float4 b4 = *(const float4*)&Bs[k * kBStr + tn * 4];
                acc[0][0] = fmaf(a4.x, b4.x, acc[0][0]); acc[0][1] = fmaf(a4.x, b4.y, acc[0][1]);
                acc[0][2] = fmaf(a4.x, b4.z, acc[0][2]); acc[0][3] = fmaf(a4.x, b4.w, acc[0][3]);
                acc[1][0] = fmaf(a4.y, b4.x, acc[1][0]); acc[1][1] = fmaf(a4.y, b4.y, acc[1][1]);
                acc[1][2] = fmaf(a4.y, b4.z, acc[1][2]); acc[1][3] = fmaf(a4.y, b4.w, acc[1][3]);
                acc[2][0] = fmaf(a4.z, b4.x, acc[2][0]); acc[2][1] = fmaf(a4.z, b4.y, acc[2][1]);
                acc[2][2] = fmaf(a4.z, b4.z, acc[2][2]); acc[2][3] = fmaf(a4.z, b4.w, acc[2][3]);
                acc[3][0] = fmaf(a4.w, b4.x, acc[3][0]); acc[3][1] = fmaf(a4.w, b4.y, acc[3][1]);
                acc[3][2] = fmaf(a4.w, b4.z, acc[3][2]); acc[3][3] = fmaf(a4.w, b4.w, acc[3][3]);
            }
        }

        float4 bias = {0, 0, 0, 0};
        if (bn == 0)      bias = *(const float4*)&cb1[tn * 4];
        else if (bn == 2) bias = *(const float4*)&sb1[tn * 4];
        #pragma unroll
        for (int i = 0; i < 4; ++i) {
            const int m = m0 + tm * 4 + i;
            if (m < M) {
                float4 o;
                o.x = acc[i][0] + bias.x; o.y = acc[i][1] + bias.y;
                o.z = acc[i][2] + bias.z; o.w = acc[i][3] + bias.w;
                *(float4*)&C[(size_t)m * 256 + bn * 64 + tn * 4] = o;
            }
        }
    } else {
        // ---------------- corr role: one block per b, 253 unique pairs ------
        float* smu = sm + kN * kXStr;
        float* sis = smu + kN;
        const int b = blockIdx.x - nGemm;

        const float4* xb4 = (const float4*)(x + (size_t)b * (kN * kF));
        for (int idx = tid; idx < kN * kF / 4; idx += 256) {
            const float4 v = xb4[idx];
            const int r = idx / 112;
            const int k = (idx - r * 112) * 4;
            float* d = sm + r * kXStr + k;
            d[0] = v.x; d[1] = v.y; d[2] = v.z; d[3] = v.w;
        }
        __syncthreads();

        {
            const int wid = tid >> 6, lane = tid & 63;
            for (int r = wid; r < kN; r += 4) {
                const float* row = sm + r * kXStr;
                float s = 0.f;
                #pragma unroll
                for (int c = 0; c < 7; ++c) s += row[c * 64 + lane];
                #pragma unroll
                for (int o = 32; o; o >>= 1) s += __shfl_xor(s, o, 64);
                const float mean = s * (1.f / 448.f);
                float ss = 0.f;
                #pragma unroll
                for (int c = 0; c < 7; ++c) { const float d = row[c * 64 + lane] - mean; ss = fmaf(d, d, ss); }
                #pragma unroll
                for (int o = 32; o; o >>= 1) ss += __shfl_xor(ss, o, 64);
                if (lane == 0) {
                    smu[r] = mean;
                    sis[r] = 1.f / (sqrtf(ss * (1.f / 447.f)) + 1e-8f);   // ddof=1
                }
            }
        }
        __syncthreads();

        if (tid < 253) {   // unique pairs i<=j, write both triangles
            int rem = tid, i = 0;
            while (rem >= kN - i) { rem -= kN - i; ++i; }
            const int j = i + rem;
            const float4* ri = (const float4*)(sm + i * kXStr);
            const float4* rj = (const float4*)(sm + j * kXStr);
            float dot = 0.f;
            for (int q = 0; q < 112; ++q) {
                const float4 a = ri[q], bq = rj[q];
                dot = fmaf(a.x, bq.x, dot); dot = fmaf(a.y, bq.y, dot);
                dot = fmaf(a.z, bq.z, dot); dot = fmaf(a.w, bq.w, dot);
            }
            const float c = (dot - 448.f * smu[i] * smu[j]) * sis[i] * sis[j] * (1.f / 448.f);
            const float ac = fabsf(c);
            g[(size_t)b * kNP + i * 22 + j] = ac;
            g[(size_t)b * kNP + j * 22 + i] = ac;
        }
    }
}

// ============ kernel 2: 2 blocks/b, slot-based (231 upper + 22 diag) ========
__global__ __launch_bounds__(256) void hgc_k2(
    const float* __restrict__ C, const float* __restrict__ g,
    const float* __restrict__ cw2, const float* __restrict__ cb2,
    const float* __restrict__ sw2, const float* __restrict__ sb2,
    const float* __restrict__ sw3, const float* __restrict__ sb3,
    const float* __restrict__ ln_g, const float* __restrict__ ln_b,
    const float* __restrict__ thr, const float* __restrict__ alpha_p,
    float* __restrict__ out)
{
    __shared__ __align__(16) float sp[4 * kN * kPStr];   // a1|a2|u1|u2
    __shared__ float sg[kNP];
    __shared__ __align__(16) float sw2s[2048];
    __shared__ float scw2[64], slng[64], slnb[64], ssw3[32], ssb2[32];
    __shared__ __align__(16) float vbuf[32 * kVStr];

    const int tid = threadIdx.x;
    const int b   = blockIdx.x >> 1;
    const int pb  = blockIdx.x & 1;

    #pragma unroll
    for (int a = 0; a < 4; ++a) {
        float* dst = sp + a * kN * kPStr;
        for (int idx = tid; idx < 352; idx += 256) {
            const int r = idx >> 4, kq = idx & 15;
            const float4 v = *(const float4*)&C[((size_t)(b * 22 + r)) * 256 + a * 64 + kq * 4];
            *(float4*)&dst[r * kPStr + kq * 4] = v;
        }
    }
    for (int idx = tid; idx < kNP; idx += 256) sg[idx] = g[(size_t)b * kNP + idx];
    {
        const float4* s4 = (const float4*)sw2;
        for (int idx = tid; idx < 512; idx += 256)
            *((float4*)(sw2s + idx * 4)) = s4[idx];
    }
    if (tid < 64)       { scw2[tid] = cw2[tid]; slng[tid] = ln_g[tid]; slnb[tid] = ln_b[tid]; }
    else if (tid < 96)  { ssw3[tid - 64] = sw3[tid - 64]; }
    else if (tid < 128) { ssb2[tid - 96] = sb2[tid - 96]; }
    __syncthreads();

    const int pl = tid >> 3;             // local slot 0..31
    const int t  = tid & 7;
    const float* sa1 = sp;
    const float* sa2 = sp + kN * kPStr;
    const float* su1 = sp + 2 * kN * kPStr;
    const float* su2 = sp + 3 * kN * kPStr;

    for (int ch = 0; ch < 4; ++ch) {
        const int s_  = pb * 128 + ch * 32 + pl;       // 0..255
        const bool valid = s_ < 253;
        const int s = valid ? s_ : 252;
        int i, j;
        if (s < 231) {                                 // strict upper: row i has 21-i entries
            int rem = s, i0 = 0;
            while (rem >= 21 - i0) { rem -= 21 - i0; ++i0; }
            i = i0; j = i0 + 1 + rem;
        } else { i = j = s - 231; }

        // w_corr for (i,j) AND (j,i): sigmoid(relu(a1_r + a2_c) . cw2 + cb2)
        float zc1 = 0.f, zc2 = 0.f;
        {
            const float* a1i = sa1 + i * kPStr + t * 8;
            const float* a2j = sa2 + j * kPStr + t * 8;
            const float* a1j = sa1 + j * kPStr + t * 8;
            const float* a2i = sa2 + i * kPStr + t * 8;
            const float4 i0 = *(const float4*)a1i, i1 = *(const float4*)(a1i + 4);
            const float4 j0 = *(const float4*)a2j, j1 = *(const float4*)(a2j + 4);
            const float4 k0 = *(const float4*)a1j, k1 = *(const float4*)(a1j + 4);
            const float4 l0 = *(const float4*)a2i, l1 = *(const float4*)(a2i + 4);
            const float4 w0 = *(const float4*)(scw2 + t * 8);
            const float4 w1 = *(const float4*)(scw2 + t * 8 + 4);
            zc1 = fmaf(fmaxf(i0.x + j0.x, 0.f), w0.x, zc1);
            zc1 = fmaf(fmaxf(i0.y + j0.y, 0.f), w0.y, zc1);
            zc1 = fmaf(fmaxf(i0.z + j0.z, 0.f), w0.z, zc1);
            zc1 = fmaf(fmaxf(i0.w + j0.w, 0.f), w0.w, zc1);
            zc1 = fmaf(fmaxf(i1.x + j1.x, 0.f), w1.x, zc1);
            zc1 = fmaf(fmaxf(i1.y + j1.y, 0.f), w1.y, zc1);
            zc1 = fmaf(fmaxf(i1.z + j1.z, 0.f), w1.z, zc1);
            zc1 = fmaf(fmaxf(i1.w + j1.w, 0.f), w1.w, zc1);
            zc2 = fmaf(fmaxf(k0.x + l0.x, 0.f), w0.x, zc2);
            zc2 = fmaf(fmaxf(k0.y + l0.y, 0.f), w0.y, zc2);
            zc2 = fmaf(fmaxf(k0.z + l0.z, 0.f), w0.z, zc2);
            zc2 = fmaf(fmaxf(k0.w + l0.w, 0.f), w0.w, zc2);
            zc2 = fmaf(fmaxf(k1.x + l1.x, 0.f), w1.x, zc2);
            zc2 = fmaf(fmaxf(k1.y + l1.y, 0.f), w1.y, zc2);
            zc2 = fmaf(fmaxf(k1.z + l1.z, 0.f), w1.z, zc2);
            zc2 = fmaf(fmaxf(k1.w + l1.w, 0.f), w1.w, zc2);
            zc1 += __shfl_xor(zc1, 1, 64); zc1 += __shfl_xor(zc1, 2, 64); zc1 += __shfl_xor(zc1, 4, 64);
            zc2 += __shfl_xor(zc2, 1, 64); zc2 += __shfl_xor(zc2, 2, 64); zc2 += __shfl_xor(zc2, 4, 64);
        }

        // semantic for (i,j) with i<=j
        float raw[8];
        float s1 = 0.f;
        {
            const float* pu1 = su1 + i * kPStr + t * 8;
            const float* pu2 = su2 + j * kPStr + t * 8;
            const float4 u0 = *(const float4*)pu1, u1v = *(const float4*)(pu1 + 4);
            const float4 v0 = *(const float4*)pu2, v1v = *(const float4*)(pu2 + 4);
            raw[0] = u0.x + v0.x; raw[1] = u0.y + v0.y; raw[2] = u0.z + v0.z; raw[3] = u0.w + v0.w;
            raw[4] = u1v.x + v1v.x; raw[5] = u1v.y + v1v.y; raw[6] = u1v.z + v1v.z; raw[7] = u1v.w + v1v.w;
            #pragma unroll
            for (int c = 0; c < 8; ++c) s1 += raw[c];
        }
        s1 += __shfl_xor(s1, 1, 64); s1 += __shfl_xor(s1, 2, 64); s1 += __shfl_xor(s1, 4, 64);
        const float mean = s1 * (1.f / 64.f);
        float s2 = 0.f;
        #pragma unroll
        for (int c = 0; c < 8; ++c) { const float d = raw[c] - mean; s2 = fmaf(d, d, s2); }
        s2 += __shfl_xor(s2, 1, 64); s2 += __shfl_xor(s2, 2, 64); s2 += __shfl_xor(s2, 4, 64);
        const float rstd = rsqrtf(s2 * (1.f / 64.f) + 1e-5f);
        {
            float* vb = vbuf + pl * kVStr + t * 8;
            float4 o0, o1;
            o0.x = fmaxf(fmaf((raw[0] - mean) * rstd, slng[t*8+0], slnb[t*8+0]), 0.f);
            o0.y = fmaxf(fmaf((raw[1] - mean) * rstd, slng[t*8+1], slnb[t*8+1]), 0.f);
            o0.z = fmaxf(fmaf((raw[2] - mean) * rstd, slng[t*8+2], slnb[t*8+2]), 0.f);
            o0.w = fmaxf(fmaf((raw[3] - mean) * rstd, slng[t*8+3], slnb[t*8+3]), 0.f);
            o1.x = fmaxf(fmaf((raw[4] - mean) * rstd, slng[t*8+4], slnb[t*8+4]), 0.f);
            o1.y = fmaxf(fmaf((raw[5] - mean) * rstd, slng[t*8+5], slnb[t*8+5]), 0.f);
            o1.z = fmaxf(fmaf((raw[6] - mean) * rstd, slng[t*8+6], slnb[t*8+6]), 0.f);
            o1.w = fmaxf(fmaf((raw[7] - mean) * rstd, slng[t*8+7], slnb[t*8+7]), 0.f);
            *(float4*)vb = o0;
            *(float4*)(vb + 4) = o1;
        }
        __syncthreads();

        // 64x32 GEMV: lane owns outputs t*4 .. t*4+3
        float4 acc = {0, 0, 0, 0};
        {
            const float* vb = vbuf + pl * kVStr;
            for (int k = 0; k < 64; ++k) {
                const float v = vb[k];
                const float4 w = *((const float4*)(sw2s + k * 32 + t * 4));
                acc.x = fmaf(v, w.x, acc.x); acc.y = fmaf(v, w.y, acc.y);
                acc.z = fmaf(v, w.z, acc.z); acc.w = fmaf(v, w.w, acc.w);
            }
        }
        float z2;
        {
            const int o0 = t * 4;
            z2  = fmaxf(acc.x + ssb2[o0 + 0], 0.f) * ssw3[o0 + 0];
            z2 += fmaxf(acc.y + ssb2[o0 + 1], 0.f) * ssw3[o0 + 1];
            z2 += fmaxf(acc.z + ssb2[o0 + 2], 0.f) * ssw3[o0 + 2];
            z2 += fmaxf(acc.w + ssb2[o0 + 3], 0.f) * ssw3[o0 + 3];
            z2 += __shfl_xor(z2, 1, 64); z2 += __shfl_xor(z2, 2, 64); z2 += __shfl_xor(z2, 4, 64);
        }

        if (valid && t == 0) {
            const float alpha = 1.f / (1.f + __expf(-alpha_p[0]));
            const float wc_ij = 1.f / (1.f + __expf(-(zc1 + cb2[0])));
            float gsem;
            if (i == j) {
                gsem = 1.f;
            } else {
                // accurate expf: this sigmoid feeds a hard threshold compare
                const float wsem = 1.f / (1.f + expf(-(z2 + sb3[0])));
                const float tt   = 1.f / (1.f + expf(-thr[0]));
                gsem = (wsem > tt) ? wsem : 0.f;
            }
            const float gc_ij = fmaf(sg[i * 22 + j], wc_ij, (i == j) ? 1.f : 0.f);
            out[(size_t)b * kNP + i * 22 + j] = fmaf(alpha, gc_ij, (1.f - alpha) * gsem);
            if (i != j) {
                const float wc_ji = 1.f / (1.f + __expf(-(zc2 + cb2[0])));
                const float gc_ji = sg[j * 22 + i] * wc_ji;
                out[(size_t)b * kNP + j * 22 + i] = fmaf(alpha, gc_ji, (1.f - alpha) * gsem);
            }
        }
        __syncthreads();   // vbuf reuse across chunks
    }
}

extern "C" void kernel_launch(void* const* d_in, const int* in_sizes, int n_in,
                              void* d_out, int out_size, void* d_ws, size_t ws_size,
                              hipStream_t stream)
{
    (void)n_in; (void)out_size; (void)ws_size;
    const float* x     = (const float*)d_in[0];
    const float* cw1   = (const float*)d_in[1];
    const float* cb1   = (const float*)d_in[2];
    const float* cw2   = (const float*)d_in[3];
    const float* cb2   = (const float*)d_in[4];
    const float* emb   = (const float*)d_in[5];
    const float* sw1   = (const float*)d_in[6];
    const float* sb1   = (const float*)d_in[7];
    const float* ln_g  = (const float*)d_in[8];
    const float* ln_b  = (const float*)d_in[9];
    const float* sw2   = (const float*)d_in[10];
    const float* sb2   = (const float*)d_in[11];
    const float* sw3   = (const float*)d_in[12];
    const float* sb3   = (const float*)d_in[13];
    const float* thr   = (const float*)d_in[14];
    const float* alpha = (const float*)d_in[15];
    float* out = (float*)d_out;
    float* ws  = (float*)d_ws;

    const int B = in_sizes[0] / (kN * kF);
    const int M = kN * B;
    const int Mtiles = (M + 63) / 64;
    const int nGemm = Mtiles * 4;

    float* C = ws;                           // M x 256
    float* g = ws + (size_t)M * 256;         // B x 484

    hipLaunchKernelGGL(hgc_k1, dim3(nGemm + B), dim3(256), 0, stream,
                       x, cw1, cb1, emb, sw1, sb1, C, g, M, Mtiles, nGemm);
    hipLaunchKernelGGL(hgc_k2, dim3(2 * B), dim3(256), 0, stream,
                       C, g, cw2, cb2, sw2, sb2, sw3, sb3, ln_g, ln_b, thr, alpha, out);
}